// Round 14
// baseline (139.164 us; speedup 1.0000x reference)
//
#include <hip/hip_runtime.h>
#include <hip/hip_bf16.h>

// Problem constants
#define B_   2
#define LQ_  2048
#define NH_  8
#define HB_  16      // NH_*B_
#define DM_  512
#define DK_  64
#define HBLQ (HB_ * LQ_)   // 32768 rows

// temper = sqrt(d_model); scores computed in log2-space:
// SCALE_T = (1/sqrt(512)) * log2(e), folded into Q at projection time
#define SCALE_T (0.04419417382415922f * 1.4426950408889634f)

typedef short s16x8 __attribute__((ext_vector_type(8)));   // 8 bf16 (4 VGPRs)
typedef float f32x4 __attribute__((ext_vector_type(4)));   // MFMA 16x16 C/D

__device__ __forceinline__ ushort f2bfbits(float f){
  __hip_bfloat16 h = __float2bfloat16(f);
  union { __hip_bfloat16 h; ushort u; } cv; cv.h = h; return cv.u;
}
__device__ __forceinline__ uint4 pack8(float4 v0, float4 v1){
  uint4 p;
  p.x = (uint)f2bfbits(v0.x) | ((uint)f2bfbits(v0.y) << 16);
  p.y = (uint)f2bfbits(v0.z) | ((uint)f2bfbits(v0.w) << 16);
  p.z = (uint)f2bfbits(v1.x) | ((uint)f2bfbits(v1.y) << 16);
  p.w = (uint)f2bfbits(v1.z) | ((uint)f2bfbits(v1.w) << 16);
  return p;
}
// async global->LDS 16B copy (vmcnt-tracked; __syncthreads drains)
__device__ __forceinline__ void gload_lds16(const void* g, void* l){
  __builtin_amdgcn_global_load_lds(
      (const __attribute__((address_space(1))) void*)g,
      (__attribute__((address_space(3))) void*)l, 16, 0, 0);
}

// 4-way partial-stat merge (absolute sums -> associative, rescale-free).
// p = 2^m / sum_total, a = argmax (min index on ties).
__device__ __forceinline__ void merge4(
    const float* __restrict__ pmP, const float* __restrict__ smP,
    const int* __restrict__ amP, long row, float& p, int& a){
  float m = pmP[row]; float s = smP[row]; int aa = amP[row];
  #pragma unroll
  for (int qq = 1; qq < 4; ++qq){
    long o = (long)qq * HBLQ + row;
    float m2 = pmP[o], s2 = smP[o]; int a2 = amP[o];
    s += s2;
    bool take = (m2 > m) || (m2 == m && a2 < aa);
    aa = take ? a2 : aa; m = take ? m2 : m;
  }
  p = exp2f(m) / s; a = aa;
}

// ---------------------------------------------------------------------------
// P0: unified prep kernel. grid (1024, 1, 9), 256 thr.  (round-12 verified)
// z=0,1,2: cast q/k/v fp32 -> bf16 [4096][512]          (1024 blocks)
// z=3,4,5: repack w{q,k,v} fp32 -> bf16 [n=h*64+ko][d]  (x<64)
// z=6    : transpose pw [n][k] fp32 -> pwt [k][n] fp32  (x<64)
// z=7    : bias2[i] = lb[i] + sum_n lw[i][512+n]*pb[n]  (x<2)
// z=8    : cast lw[:, :512] -> bf16 lwb1 [512][512]     (x<64)
// ---------------------------------------------------------------------------
__global__ __launch_bounds__(256) void prep_all(
    const float* __restrict__ q, const float* __restrict__ k, const float* __restrict__ v,
    const float* __restrict__ wq, const float* __restrict__ wk, const float* __restrict__ wv,
    const float* __restrict__ pw, const float* __restrict__ lw,
    const float* __restrict__ pb, const float* __restrict__ lb,
    ushort* __restrict__ qb, ushort* __restrict__ kb, ushort* __restrict__ vb,
    ushort* __restrict__ wqT, ushort* __restrict__ wkT, ushort* __restrict__ wvT,
    float* __restrict__ pwt, float* __restrict__ bias2, ushort* __restrict__ lwb1){
  const int z = blockIdx.z;
  const int x = blockIdx.x;
  const int tid = threadIdx.x;
  __shared__ float t[64][65];

  if (z < 3){
    const float* src = (z == 0) ? q : (z == 1) ? k : v;
    ushort* dst      = (z == 0) ? qb : (z == 1) ? kb : vb;
    long i = (long)x * 256 + tid;     // 262144 threads, 8 elts each
    float4 a = *(const float4*)(src + i * 8);
    float4 b = *(const float4*)(src + i * 8 + 4);
    *(uint4*)(dst + i * 8) = pack8(a, b);
  } else if (z < 6){
    if (x >= 64) return;
    const float* src = (z == 3) ? wq : (z == 4) ? wk : wv;
    ushort* dst      = (z == 3) ? wqT : (z == 4) ? wkT : wvT;
    const int h  = x >> 3;
    const int d0 = (x & 7) * 64;
    for (int i = tid; i < 64 * 16; i += 256){
      int dd = i >> 4, c4 = (i & 15) * 4;
      float4 vv = *(const float4*)(src + ((long)(h * DM_ + d0 + dd)) * DK_ + c4);
      t[dd][c4] = vv.x; t[dd][c4+1] = vv.y; t[dd][c4+2] = vv.z; t[dd][c4+3] = vv.w;
    }
    __syncthreads();
    for (int i = tid; i < 64 * 16; i += 256){
      int ko = i >> 4, g = (i & 15) * 4;
      ushort4 u;
      u.x = f2bfbits(t[g+0][ko]); u.y = f2bfbits(t[g+1][ko]);
      u.z = f2bfbits(t[g+2][ko]); u.w = f2bfbits(t[g+3][ko]);
      *(ushort4*)(dst + ((long)(h * DK_ + ko)) * DM_ + d0 + g) = u;
    }
  } else if (z == 6){
    if (x >= 64) return;
    const int n0 = (x >> 3) * 64;
    const int k0 = (x & 7) * 64;
    for (int i = tid; i < 64 * 16; i += 256){
      int nn = i >> 4, c4 = (i & 15) * 4;
      float4 vv = *(const float4*)(pw + (long)(n0 + nn) * DM_ + k0 + c4);
      t[nn][c4] = vv.x; t[nn][c4+1] = vv.y; t[nn][c4+2] = vv.z; t[nn][c4+3] = vv.w;
    }
    __syncthreads();
    for (int i = tid; i < 64 * 16; i += 256){
      int kk = i >> 4, c4 = (i & 15) * 4;
      float4 vv;
      vv.x = t[c4+0][kk]; vv.y = t[c4+1][kk]; vv.z = t[c4+2][kk]; vv.w = t[c4+3][kk];
      *(float4*)(pwt + (long)(k0 + kk) * DM_ + n0 + c4) = vv;
    }
  } else if (z == 7){
    if (x >= 2) return;
    int i = x * 256 + tid;
    float acc = 0.f;
    const float* row = lw + (long)i * 1024 + 512;
    for (int n = 0; n < DM_; ++n) acc += row[n] * pb[n];
    bias2[i] = lb[i] + acc;
  } else {
    if (x >= 64) return;
    for (int rep = 0; rep < 2; ++rep){
      int idx = rep * 16384 + x * 256 + tid;
      int row = idx >> 6, g = (idx & 63) * 8;
      const float* s = lw + (long)row * 1024 + g;
      float4 a = *(const float4*)(s);
      float4 b = *(const float4*)(s + 4);
      *(uint4*)(lwb1 + (long)row * DM_ + g) = pack8(a, b);
    }
  }
}

// ---------------------------------------------------------------------------
// PH2: combined head-projection GEMMs + W2 GEMM, 1600 blocks (round-12 verified)
// ---------------------------------------------------------------------------
__global__ __launch_bounds__(256) void phase2_k(
    const ushort* __restrict__ qb, const ushort* __restrict__ kb, const ushort* __restrict__ vb,
    const ushort* __restrict__ wqT, const ushort* __restrict__ wkT, const ushort* __restrict__ wvT,
    ushort* __restrict__ qhb, ushort* __restrict__ khb, float* __restrict__ vh,
    const float* __restrict__ lw, const float* __restrict__ pwt, ushort* __restrict__ w2b){
  const int tid = threadIdx.x;
  const int wid = tid >> 6, lane = tid & 63;
  const int l15 = lane & 15, l4 = lane >> 4;

  __shared__ ushort as_[64 * 64];
  __shared__ ushort bs_[64 * 64];

  f32x4 acc[4];
  #pragma unroll
  for (int ct = 0; ct < 4; ++ct){ acc[ct][0]=0.f; acc[ct][1]=0.f; acc[ct][2]=0.f; acc[ct][3]=0.f; }

  if (blockIdx.x < 1536){
    const int which = blockIdx.x / 512;
    const int bid   = blockIdx.x % 512;
    const ushort* A  = (which == 0) ? qb : (which == 1) ? kb : vb;
    const ushort* Bt = (which == 0) ? wqT : (which == 1) ? wkT : wvT;

    const int lt  = (bid & 7) * 64 + (bid >> 3);
    const int m0  = (lt >> 3) * 64;
    const int n0  = (lt & 7) * 64;

    const int i0 = tid, i1 = tid + 256;
    const int r0 = i0 >> 3, cg0 = (i0 & 7) ^ (r0 & 7);
    const int r1 = i1 >> 3, cg1 = (i1 & 7) ^ (r1 & 7);

    for (int k0 = 0; k0 < DM_; k0 += 64){
      __syncthreads();
      gload_lds16(A  + (long)(m0 + r0) * DM_ + k0 + cg0 * 8, (char*)as_ + i0 * 16);
      gload_lds16(A  + (long)(m0 + r1) * DM_ + k0 + cg1 * 8, (char*)as_ + i1 * 16);
      gload_lds16(Bt + (long)(n0 + r0) * DM_ + k0 + cg0 * 8, (char*)bs_ + i0 * 16);
      gload_lds16(Bt + (long)(n0 + r1) * DM_ + k0 + cg1 * 8, (char*)bs_ + i1 * 16);
      __syncthreads();

      const char* arow = (const char*)as_ + (wid * 16 + l15) * 128;
      const int swz = (l15 & 7) << 4;
      s16x8 a0 = *(const s16x8*)(arow + ((l4 * 16) ^ swz));
      s16x8 a1 = *(const s16x8*)(arow + ((64 + l4 * 16) ^ swz));
      #pragma unroll
      for (int ct = 0; ct < 4; ++ct){
        const char* brow = (const char*)bs_ + (ct * 16 + l15) * 128;
        s16x8 b0 = *(const s16x8*)(brow + ((l4 * 16) ^ swz));
        s16x8 b1 = *(const s16x8*)(brow + ((64 + l4 * 16) ^ swz));
        acc[ct] = __builtin_amdgcn_mfma_f32_16x16x32_bf16(a0, b0, acc[ct], 0, 0, 0);
        acc[ct] = __builtin_amdgcn_mfma_f32_16x16x32_bf16(a1, b1, acc[ct], 0, 0, 0);
      }
    }

    #pragma unroll
    for (int ct = 0; ct < 4; ++ct){
      int col = n0 + ct * 16 + l15;
      int h = col >> 6, ko = col & 63;
      #pragma unroll
      for (int r = 0; r < 4; ++r){
        int m = m0 + wid * 16 + l4 * 4 + r;
        int b = m >> 11, l = m & 2047;
        long idx = (((long)h * B_ + b) * LQ_ + l) * DK_ + ko;
        if (which == 0)      qhb[idx] = f2bfbits(acc[ct][r] * SCALE_T);
        else if (which == 1) khb[idx] = f2bfbits(acc[ct][r]);
        else                 vh[idx]  = acc[ct][r];
      }
    }
  } else {
    const int t_ = blockIdx.x - 1536;        // [0,64)
    const int m0 = (t_ >> 3) * 64;
    const int n0 = (t_ & 7) * 64;

    for (int k0 = 0; k0 < DM_; k0 += 64){
      __syncthreads();
      for (int i = tid; i < 512; i += 256){
        int r = i >> 3, c = i & 7;
        const float* sa = lw + (long)(m0 + r) * 1024 + 512 + k0 + c * 8;
        float4 a0 = *(const float4*)(sa);
        float4 a1 = *(const float4*)(sa + 4);
        *(uint4*)((char*)as_ + r * 128 + ((c * 16) ^ ((r & 7) << 4))) = pack8(a0, a1);
        const float* sb = pwt + (long)(n0 + r) * DM_ + k0 + c * 8;
        float4 b0 = *(const float4*)(sb);
        float4 b1 = *(const float4*)(sb + 4);
        *(uint4*)((char*)bs_ + r * 128 + ((c * 16) ^ ((r & 7) << 4))) = pack8(b0, b1);
      }
      __syncthreads();

      const char* arow = (const char*)as_ + (wid * 16 + l15) * 128;
      const int swz = (l15 & 7) << 4;
      s16x8 a0 = *(const s16x8*)(arow + ((l4 * 16) ^ swz));
      s16x8 a1 = *(const s16x8*)(arow + ((64 + l4 * 16) ^ swz));
      #pragma unroll
      for (int ct = 0; ct < 4; ++ct){
        const char* brow = (const char*)bs_ + (ct * 16 + l15) * 128;
        s16x8 b0 = *(const s16x8*)(brow + ((l4 * 16) ^ swz));
        s16x8 b1 = *(const s16x8*)(brow + ((64 + l4 * 16) ^ swz));
        acc[ct] = __builtin_amdgcn_mfma_f32_16x16x32_bf16(a0, b0, acc[ct], 0, 0, 0);
        acc[ct] = __builtin_amdgcn_mfma_f32_16x16x32_bf16(a1, b1, acc[ct], 0, 0, 0);
      }
    }

    #pragma unroll
    for (int ct = 0; ct < 4; ++ct){
      int col = n0 + ct * 16 + l15;
      #pragma unroll
      for (int r = 0; r < 4; ++r){
        int m = m0 + wid * 16 + l4 * 4 + r;
        w2b[(long)m * DM_ + col] = f2bfbits(acc[ct][r]);
      }
    }
  }
}

// ---------------------------------------------------------------------------
// K2: MFMA scores + branch-free top-1 softmax, 4-way j-split.
// 2048 blocks: quarter = bid&3 (8 jt tiles), hb = (bid>>2)&15, q0 = (bid>>6)*64.
// Writes PARTIAL stats (raw m, absolute sum, argmax) to pmP/smP/amP[quarter].
// Body otherwise round-12 verbatim.
// ---------------------------------------------------------------------------
__global__ __launch_bounds__(256) void attn_split_k(
    const ushort* __restrict__ qhb, const ushort* __restrict__ khb,
    float* __restrict__ pmP, float* __restrict__ smP, int* __restrict__ amP){
  const int quarter = blockIdx.x & 3;
  const int hb = (blockIdx.x >> 2) & 15;
  const int q0 = (blockIdx.x >> 6) * 64;
  const int tid = threadIdx.x;
  const int wid  = tid >> 6;
  const int lane = tid & 63;
  const int l15  = lane & 15;
  const int l4   = lane >> 4;

  __shared__ ushort ks[64 * 64];

  const ushort* qrow = qhb + ((long)hb * LQ_ + q0 + wid * 16 + l15) * DK_;
  s16x8 aq0 = *(const s16x8*)(qrow +  0 + l4 * 8);
  s16x8 aq1 = *(const s16x8*)(qrow + 32 + l4 * 8);

  const int i0 = tid, i1 = tid + 256;
  const int r0 = i0 >> 3, cg0 = (i0 & 7) ^ (r0 & 7);
  const int r1 = i1 >> 3, cg1 = (i1 & 7) ^ (r1 & 7);

  float m[4], sum[4]; int arg[4];
  #pragma unroll
  for (int r = 0; r < 4; ++r){ m[r] = -1e30f; sum[r] = 0.f; arg[r] = 0; }

  const ushort* kb0 = khb + (long)hb * LQ_ * DK_;
  for (int jt = quarter * 8; jt < quarter * 8 + 8; ++jt){
    __syncthreads();
    const ushort* kbase = kb0 + (long)(jt * 64) * DK_;
    gload_lds16(kbase + r0 * 64 + cg0 * 8, (char*)ks + i0 * 16);
    gload_lds16(kbase + r1 * 64 + cg1 * 8, (char*)ks + i1 * 16);
    __syncthreads();

    f32x4 acc[4];
    #pragma unroll
    for (int ct = 0; ct < 4; ++ct){
      int row = ct * 16 + l15;
      const char* base = (const char*)ks + row * 128;
      int swz = (row & 7) << 4;
      s16x8 b0 = *(const s16x8*)(base + ((l4 * 16) ^ swz));
      s16x8 b1 = *(const s16x8*)(base + ((64 + l4 * 16) ^ swz));
      f32x4 c; c[0]=0.f; c[1]=0.f; c[2]=0.f; c[3]=0.f;
      c = __builtin_amdgcn_mfma_f32_16x16x32_bf16(aq0, b0, c, 0, 0, 0);
      c = __builtin_amdgcn_mfma_f32_16x16x32_bf16(aq1, b1, c, 0, 0, 0);
      acc[ct] = c;
    }

    #pragma unroll
    for (int ct = 0; ct < 4; ++ct){
      int col = jt * 64 + ct * 16 + l15;
      #pragma unroll
      for (int r = 0; r < 4; ++r){
        float t = acc[ct][r];
        sum[r] += exp2f(t);
        bool gt = t > m[r];
        arg[r] = gt ? col : arg[r];
        m[r]   = gt ? t : m[r];
      }
    }
  }

  #pragma unroll
  for (int off = 1; off < 16; off <<= 1){
    #pragma unroll
    for (int r = 0; r < 4; ++r){
      float m2 = __shfl_xor(m[r], off);
      float s2 = __shfl_xor(sum[r], off);
      int   a2 = __shfl_xor(arg[r], off);
      sum[r] += s2;
      bool take = (m2 > m[r]) || (m2 == m[r] && a2 < arg[r]);
      arg[r] = take ? a2 : arg[r];
      m[r]   = take ? m2 : m[r];
    }
  }

  if (l15 == 0){
    long qoff = (long)quarter * HBLQ;
    #pragma unroll
    for (int r = 0; r < 4; ++r){
      long row = (long)hb * LQ_ + q0 + wid * 16 + l4 * 4 + r;
      pmP[qoff + row] = m[r];
      smP[qoff + row] = sum[r];
      amP[qoff + row] = arg[r];
    }
  }
}

// ---------------------------------------------------------------------------
// Final GEMM body (round-12 verified, stats via merge4):
// out0 = [q | p*vh[amax]] @ [lwb1|w2b]^T + bias2
// ---------------------------------------------------------------------------
__device__ __forceinline__ void gemm_final_body(
    int bid, const float* __restrict__ q, const float* __restrict__ vh,
    const ushort* __restrict__ lwb1, const ushort* __restrict__ w2b,
    const float* __restrict__ bias2, const float* __restrict__ pmP,
    const float* __restrict__ smP, const int* __restrict__ amP,
    float* __restrict__ out0){
  const int lt  = (bid & 7) * 64 + (bid >> 3);
  const int m0  = (lt >> 3) * 64;
  const int n0  = (lt & 7) * 64;

  const int tid = threadIdx.x;
  const int wid = tid >> 6, lane = tid & 63;
  const int l15 = lane & 15, l4 = lane >> 4;

  __shared__ ushort as_[64 * 64];
  __shared__ ushort bs_[64 * 64];

  f32x4 acc[4];
  #pragma unroll
  for (int ct = 0; ct < 4; ++ct){ acc[ct][0]=0.f; acc[ct][1]=0.f; acc[ct][2]=0.f; acc[ct][3]=0.f; }

  for (int k0 = 0; k0 < 2 * DM_; k0 += 64){
    __syncthreads();
    if (k0 < DM_){
      for (int i = tid; i < 512; i += 256){
        int r = i >> 3, c = i & 7;
        const float* sa = q + (long)(m0 + r) * DM_ + k0 + c * 8;
        float4 a0 = *(const float4*)(sa);
        float4 a1 = *(const float4*)(sa + 4);
        *(uint4*)((char*)as_ + r * 128 + ((c * 16) ^ ((r & 7) << 4))) = pack8(a0, a1);
        uint4 bv = *(const uint4*)(lwb1 + (long)(n0 + r) * DM_ + k0 + c * 8);
        *(uint4*)((char*)bs_ + r * 128 + ((c * 16) ^ ((r & 7) << 4))) = bv;
      }
    } else {
      const int kk = k0 - DM_;
      const int h  = kk >> 6;          // head is uniform across the tile
      for (int i = tid; i < 512; i += 256){
        int r = i >> 3, c = i & 7;
        int mm = m0 + r;
        int b = mm >> 11, l = mm & 2047;
        long hbrow = (long)(h * B_ + b) * LQ_;
        float p; int a;
        merge4(pmP, smP, amP, hbrow + l, p, a);
        const float* vrow = vh + (hbrow + a) * DK_ + c * 8;
        float4 a0 = *(const float4*)(vrow);
        float4 a1 = *(const float4*)(vrow + 4);
        a0.x *= p; a0.y *= p; a0.z *= p; a0.w *= p;
        a1.x *= p; a1.y *= p; a1.z *= p; a1.w *= p;
        *(uint4*)((char*)as_ + r * 128 + ((c * 16) ^ ((r & 7) << 4))) = pack8(a0, a1);
        uint4 bv = *(const uint4*)(w2b + (long)(n0 + r) * DM_ + kk + c * 8);
        *(uint4*)((char*)bs_ + r * 128 + ((c * 16) ^ ((r & 7) << 4))) = bv;
      }
    }
    __syncthreads();

    const char* arow = (const char*)as_ + (wid * 16 + l15) * 128;
    const int swz = (l15 & 7) << 4;
    s16x8 a0 = *(const s16x8*)(arow + ((l4 * 16) ^ swz));
    s16x8 a1 = *(const s16x8*)(arow + ((64 + l4 * 16) ^ swz));
    #pragma unroll
    for (int ct = 0; ct < 4; ++ct){
      const char* brow = (const char*)bs_ + (ct * 16 + l15) * 128;
      s16x8 b0 = *(const s16x8*)(brow + ((l4 * 16) ^ swz));
      s16x8 b1 = *(const s16x8*)(brow + ((64 + l4 * 16) ^ swz));
      acc[ct] = __builtin_amdgcn_mfma_f32_16x16x32_bf16(a0, b0, acc[ct], 0, 0, 0);
      acc[ct] = __builtin_amdgcn_mfma_f32_16x16x32_bf16(a1, b1, acc[ct], 0, 0, 0);
    }
  }

  #pragma unroll
  for (int ct = 0; ct < 4; ++ct){
    int col = n0 + ct * 16 + l15;
    float bb = bias2[col];
    #pragma unroll
    for (int r = 0; r < 4; ++r){
      int mm = m0 + wid * 16 + l4 * 4 + r;
      out0[(long)mm * DM_ + col] = acc[ct][r] + bb;
    }
  }
}

// ---------------------------------------------------------------------------
// Zero + scatter one group of 4 attn rows (round-12 verified, stats via merge4)
// ---------------------------------------------------------------------------
__device__ __forceinline__ void write_attn_body(
    int bid, const float* __restrict__ pmP, const float* __restrict__ smP,
    const int* __restrict__ amP, float* __restrict__ attn_out){
  int row  = bid * 4 + (threadIdx.x >> 6);
  int lane = threadIdx.x & 63;
  float p; int a;
  merge4(pmP, smP, amP, row, p, a);
  float4* rowp = (float4*)(attn_out + (long)row * LQ_);
  #pragma unroll
  for (int i = 0; i < 8; ++i){
    int f4idx = i * 64 + lane;
    int col0  = f4idx * 4;
    float4 z = make_float4(0.f, 0.f, 0.f, 0.f);
    if (a >= col0 && a < col0 + 4){
      int r = a - col0;
      if      (r == 0) z.x = p;
      else if (r == 1) z.y = p;
      else if (r == 2) z.z = p;
      else             z.w = p;
    }
    rowp[f4idx] = z;
  }
}

// Standalone kernels (legacy path)
__global__ __launch_bounds__(256) void gemm_final_k(
    const float* __restrict__ q, const float* __restrict__ vh,
    const ushort* __restrict__ lwb1, const ushort* __restrict__ w2b,
    const float* __restrict__ bias2, const float* __restrict__ pmP,
    const float* __restrict__ smP, const int* __restrict__ amP,
    float* __restrict__ out0){
  gemm_final_body(blockIdx.x, q, vh, lwb1, w2b, bias2, pmP, smP, amP, out0);
}
__global__ __launch_bounds__(256) void write_attn_k(
    const float* __restrict__ pmP, const float* __restrict__ smP,
    const int* __restrict__ amP, float* __restrict__ attn_out){
  write_attn_body(blockIdx.x, pmP, smP, amP, attn_out);
}

// Fused heterogeneous dispatch (scratch fully in d_ws): blocks 0..511 = GEMM,
// 512..8703 = attn-region zero+scatter. No block reads the attn region.
__global__ __launch_bounds__(256) void final_fused_k(
    const float* __restrict__ q, const float* __restrict__ vh,
    const ushort* __restrict__ lwb1, const ushort* __restrict__ w2b,
    const float* __restrict__ bias2, const float* __restrict__ pmP,
    const float* __restrict__ smP, const int* __restrict__ amP,
    float* __restrict__ out0, float* __restrict__ attn_out){
  if (blockIdx.x < 512)
    gemm_final_body(blockIdx.x, q, vh, lwb1, w2b, bias2, pmP, smP, amP, out0);
  else
    write_attn_body(blockIdx.x - 512, pmP, smP, amP, attn_out);
}

// ---------------------------------------------------------------------------
extern "C" void kernel_launch(void* const* d_in, const int* in_sizes, int n_in,
                              void* d_out, int out_size, void* d_ws, size_t ws_size,
                              hipStream_t stream){
  const float* q  = (const float*)d_in[0];
  const float* k  = (const float*)d_in[1];
  const float* v  = (const float*)d_in[2];
  const float* wq = (const float*)d_in[3];
  const float* wk = (const float*)d_in[4];
  const float* wv = (const float*)d_in[5];
  const float* pw = (const float*)d_in[6];
  const float* pb = (const float*)d_in[7];
  const float* lw = (const float*)d_in[8];
  const float* lb = (const float*)d_in[9];

  float* out0     = (float*)d_out;                    // (2,2048,512)
  float* attn_out = out0 + (long)B_ * LQ_ * DM_;      // 32768 rows x 2048 floats

  // Partial stats always in d_ws: pmP/smP/amP, 4 quarters each (1.5 MB total).
  float* pmP = (float*)d_ws;                           // 4*32768 floats
  float* smP = pmP + 4L * HBLQ;                        // 4*32768 floats
  int*   amP = (int*)(smP + 4L * HBLQ);                // 4*32768 ints

  const size_t WS_FUSED_NEED = (size_t)HBLQ * 4 * 12    // partial stats
                             + (size_t)DM_*4 + 4096     // bias2 + pad
                             + (size_t)HB_*LQ_*DK_*4    // vh
                             + (size_t)DM_*DM_*2*2;     // lwb1 + w2b
  const bool fused = (ws_size >= WS_FUSED_NEED + (1u<<20));

  float *vh, *bias2; ushort *lwb1, *w2b;
  if (fused){
    float* p = (float*)(amP + 4L * HBLQ);
    bias2 = p;                        p += DM_ + 256;
    vh    = p;                        p += (long)HB_ * LQ_ * DK_;
    lwb1  = (ushort*)p;
    w2b   = lwb1 + (long)DM_ * DM_;
  } else {
    vh    = attn_out;
    bias2 = vh + (long)HB_ * LQ_ * DK_;
    lwb1  = (ushort*)(bias2 + DM_ + 256);
    w2b   = lwb1 + (long)DM_ * DM_;
  }

  // Scratch only read BEFORE the final dispatch lives in the attn region.
  ushort* base = fused ? (ushort*)attn_out : (w2b + (long)DM_ * DM_);
  ushort* wqT  = base;
  ushort* wkT  = wqT + (long)DM_ * DM_;
  ushort* wvT  = wkT + (long)DM_ * DM_;
  float*  pwt  = (float*)(wvT + (long)DM_ * DM_);
  ushort* qhb  = (ushort*)(pwt + (long)DM_ * DM_);
  ushort* khb  = qhb + (long)HB_ * LQ_ * DK_;
  ushort* qb   = khb + (long)HB_ * LQ_ * DK_;          // bf16 [4096][512]
  ushort* kb   = qb  + (long)4096 * DM_;
  ushort* vb   = kb  + (long)4096 * DM_;
  // attn-region scratch total ~26 MB << 268 MB

  // 1) prep: qkv casts, weight repacks, pw transpose, bias2, lw1 cast
  prep_all<<<dim3(1024, 1, 9), 256, 0, stream>>>(
      q, k, v, wq, wk, wv, pw, lw, pb, lb,
      qb, kb, vb, wqT, wkT, wvT, pwt, bias2, lwb1);

  // 2) head projections + W2 in one launch
  phase2_k<<<1600, 256, 0, stream>>>(
      qb, kb, vb, wqT, wkT, wvT, qhb, khb, vh, lw, pwt, w2b);

  // 3) MFMA scores + top-1 softmax, 4-way j-split (2048 blocks, partial stats)
  attn_split_k<<<2048, 256, 0, stream>>>(qhb, khb, pmP, smP, amP);

  // 4) final GEMM + attn-region write (consumers merge the 4 partials inline)
  if (fused){
    final_fused_k<<<512 + HB_*LQ_/4, 256, 0, stream>>>(
        q, vh, lwb1, w2b, bias2, pmP, smP, amP, out0, attn_out);
  } else {
    gemm_final_k<<<512, 256, 0, stream>>>(q, vh, lwb1, w2b, bias2, pmP, smP, amP, out0);
    write_attn_k<<<HB_*LQ_/4, 256, 0, stream>>>(pmP, smP, amP, attn_out);
  }
}

// Round 15
// 129.052 us; speedup vs baseline: 1.0784x; 1.0784x over previous
//
#include <hip/hip_runtime.h>
#include <hip/hip_bf16.h>

// Problem constants
#define B_   2
#define LQ_  2048
#define NH_  8
#define HB_  16      // NH_*B_
#define DM_  512
#define DK_  64

// temper = sqrt(d_model); scores computed in log2-space:
// SCALE_T = (1/sqrt(512)) * log2(e), folded into Q at projection time
#define SCALE_T (0.04419417382415922f * 1.4426950408889634f)

typedef short s16x8 __attribute__((ext_vector_type(8)));   // 8 bf16 (4 VGPRs)
typedef float f32x4 __attribute__((ext_vector_type(4)));   // MFMA 16x16 C/D

__device__ __forceinline__ ushort f2bfbits(float f){
  __hip_bfloat16 h = __float2bfloat16(f);
  union { __hip_bfloat16 h; ushort u; } cv; cv.h = h; return cv.u;
}
__device__ __forceinline__ uint4 pack8(float4 v0, float4 v1){
  uint4 p;
  p.x = (uint)f2bfbits(v0.x) | ((uint)f2bfbits(v0.y) << 16);
  p.y = (uint)f2bfbits(v0.z) | ((uint)f2bfbits(v0.w) << 16);
  p.z = (uint)f2bfbits(v1.x) | ((uint)f2bfbits(v1.y) << 16);
  p.w = (uint)f2bfbits(v1.z) | ((uint)f2bfbits(v1.w) << 16);
  return p;
}
// async global->LDS 16B copy (vmcnt-tracked; __syncthreads drains)
__device__ __forceinline__ void gload_lds16(const void* g, void* l){
  __builtin_amdgcn_global_load_lds(
      (const __attribute__((address_space(1))) void*)g,
      (__attribute__((address_space(3))) void*)l, 16, 0, 0);
}

// ---------------------------------------------------------------------------
// P0: weight prep. grid (64,1,6), 256 thr  (round-13-verified bodies)
// z=0,1,2: repack w{q,k,v} fp32 -> bf16 [n=h*64+ko][d]
// z=3    : transpose pw [n][k] fp32 -> pwt [k][n] fp32
// z=4    : bias2[i] = lb[i] + sum_n lw[i][512+n]*pb[n]   (x<2)
// z=5    : cast lw[:, :512] -> bf16 lwb1
// ---------------------------------------------------------------------------
__global__ __launch_bounds__(256) void prep_all(
    const float* __restrict__ wq, const float* __restrict__ wk, const float* __restrict__ wv,
    const float* __restrict__ pw, const float* __restrict__ lw,
    const float* __restrict__ pb, const float* __restrict__ lb,
    ushort* __restrict__ wqT, ushort* __restrict__ wkT, ushort* __restrict__ wvT,
    float* __restrict__ pwt, float* __restrict__ bias2, ushort* __restrict__ lwb1){
  const int z = blockIdx.z;
  const int x = blockIdx.x;
  const int tid = threadIdx.x;
  __shared__ float t[64][65];

  if (z < 3){
    const float* src = (z == 0) ? wq : (z == 1) ? wk : wv;
    ushort* dst      = (z == 0) ? wqT : (z == 1) ? wkT : wvT;
    const int h  = x >> 3;
    const int d0 = (x & 7) * 64;
    for (int i = tid; i < 64 * 16; i += 256){
      int dd = i >> 4, c4 = (i & 15) * 4;
      float4 vv = *(const float4*)(src + ((long)(h * DM_ + d0 + dd)) * DK_ + c4);
      t[dd][c4] = vv.x; t[dd][c4+1] = vv.y; t[dd][c4+2] = vv.z; t[dd][c4+3] = vv.w;
    }
    __syncthreads();
    for (int i = tid; i < 64 * 16; i += 256){
      int ko = i >> 4, g = (i & 15) * 4;
      ushort4 u;
      u.x = f2bfbits(t[g+0][ko]); u.y = f2bfbits(t[g+1][ko]);
      u.z = f2bfbits(t[g+2][ko]); u.w = f2bfbits(t[g+3][ko]);
      *(ushort4*)(dst + ((long)(h * DK_ + ko)) * DM_ + d0 + g) = u;
    }
  } else if (z == 3){
    const int n0 = (x >> 3) * 64;
    const int k0 = (x & 7) * 64;
    for (int i = tid; i < 64 * 16; i += 256){
      int nn = i >> 4, c4 = (i & 15) * 4;
      float4 vv = *(const float4*)(pw + (long)(n0 + nn) * DM_ + k0 + c4);
      t[nn][c4] = vv.x; t[nn][c4+1] = vv.y; t[nn][c4+2] = vv.z; t[nn][c4+3] = vv.w;
    }
    __syncthreads();
    for (int i = tid; i < 64 * 16; i += 256){
      int kk = i >> 4, c4 = (i & 15) * 4;
      float4 vv;
      vv.x = t[c4+0][kk]; vv.y = t[c4+1][kk]; vv.z = t[c4+2][kk]; vv.w = t[c4+3][kk];
      *(float4*)(pwt + (long)(k0 + kk) * DM_ + n0 + c4) = vv;
    }
  } else if (z == 4){
    if (x >= 2) return;
    int i = x * 256 + tid;
    float acc = 0.f;
    const float* row = lw + (long)i * 1024 + 512;
    for (int n = 0; n < DM_; ++n) acc += row[n] * pb[n];
    bias2[i] = lb[i] + acc;
  } else {
    for (int rep = 0; rep < 2; ++rep){
      int idx = rep * 16384 + x * 256 + tid;
      int row = idx >> 6, g = (idx & 63) * 8;
      const float* s = lw + (long)row * 1024 + g;
      float4 a = *(const float4*)(s);
      float4 b = *(const float4*)(s + 4);
      *(uint4*)(lwb1 + (long)row * DM_ + g) = pack8(a, b);
    }
  }
}

// ---------------------------------------------------------------------------
// PH2: qkv GEMMs (cast-on-stage A fp32, bf16 B copy — round-13-verified body)
// + W2 GEMM. blocks: [0,1536) qkv | [1536,1600) w2.
// ---------------------------------------------------------------------------
__global__ __launch_bounds__(256) void phase2_k(
    const float* __restrict__ q, const float* __restrict__ k, const float* __restrict__ v,
    const ushort* __restrict__ wqT, const ushort* __restrict__ wkT, const ushort* __restrict__ wvT,
    ushort* __restrict__ qhb, ushort* __restrict__ khb, float* __restrict__ vh,
    const float* __restrict__ lw, const float* __restrict__ pwt, ushort* __restrict__ w2b){
  const int tid = threadIdx.x;
  const int wid = tid >> 6, lane = tid & 63;
  const int l15 = lane & 15, l4 = lane >> 4;

  __shared__ ushort as_[64 * 64];
  __shared__ ushort bs_[64 * 64];

  f32x4 acc[4];
  #pragma unroll
  for (int ct = 0; ct < 4; ++ct){ acc[ct][0]=0.f; acc[ct][1]=0.f; acc[ct][2]=0.f; acc[ct][3]=0.f; }

  if (blockIdx.x < 1536){
    const int which = blockIdx.x / 512;
    const int bid   = blockIdx.x % 512;
    const float* A   = (which == 0) ? q : (which == 1) ? k : v;
    const ushort* Bt = (which == 0) ? wqT : (which == 1) ? wkT : wvT;

    const int lt  = (bid & 7) * 64 + (bid >> 3);
    const int m0  = (lt >> 3) * 64;
    const int n0  = (lt & 7) * 64;

    for (int k0 = 0; k0 < DM_; k0 += 64){
      __syncthreads();
      for (int i = tid; i < 512; i += 256){
        int r = i >> 3, c = i & 7;
        const float* sa = A + (long)(m0 + r) * DM_ + k0 + c * 8;
        float4 a0 = *(const float4*)(sa);
        float4 a1 = *(const float4*)(sa + 4);
        *(uint4*)((char*)as_ + r * 128 + ((c * 16) ^ ((r & 7) << 4))) = pack8(a0, a1);
        uint4 bv = *(const uint4*)(Bt + (long)(n0 + r) * DM_ + k0 + c * 8);
        *(uint4*)((char*)bs_ + r * 128 + ((c * 16) ^ ((r & 7) << 4))) = bv;
      }
      __syncthreads();

      const char* arow = (const char*)as_ + (wid * 16 + l15) * 128;
      const int swz = (l15 & 7) << 4;
      s16x8 a0 = *(const s16x8*)(arow + ((l4 * 16) ^ swz));
      s16x8 a1 = *(const s16x8*)(arow + ((64 + l4 * 16) ^ swz));
      #pragma unroll
      for (int ct = 0; ct < 4; ++ct){
        const char* brow = (const char*)bs_ + (ct * 16 + l15) * 128;
        s16x8 b0 = *(const s16x8*)(brow + ((l4 * 16) ^ swz));
        s16x8 b1 = *(const s16x8*)(brow + ((64 + l4 * 16) ^ swz));
        acc[ct] = __builtin_amdgcn_mfma_f32_16x16x32_bf16(a0, b0, acc[ct], 0, 0, 0);
        acc[ct] = __builtin_amdgcn_mfma_f32_16x16x32_bf16(a1, b1, acc[ct], 0, 0, 0);
      }
    }

    #pragma unroll
    for (int ct = 0; ct < 4; ++ct){
      int col = n0 + ct * 16 + l15;
      int h = col >> 6, ko = col & 63;
      #pragma unroll
      for (int r = 0; r < 4; ++r){
        int m = m0 + wid * 16 + l4 * 4 + r;
        int b = m >> 11, l = m & 2047;
        long idx = (((long)h * B_ + b) * LQ_ + l) * DK_ + ko;
        if (which == 0)      qhb[idx] = f2bfbits(acc[ct][r] * SCALE_T);
        else if (which == 1) khb[idx] = f2bfbits(acc[ct][r]);
        else                 vh[idx]  = acc[ct][r];
      }
    }
  } else {
    const int t_ = blockIdx.x - 1536;        // [0,64)
    const int m0 = (t_ >> 3) * 64;
    const int n0 = (t_ & 7) * 64;

    for (int k0 = 0; k0 < DM_; k0 += 64){
      __syncthreads();
      for (int i = tid; i < 512; i += 256){
        int r = i >> 3, c = i & 7;
        const float* sa = lw + (long)(m0 + r) * 1024 + 512 + k0 + c * 8;
        float4 a0 = *(const float4*)(sa);
        float4 a1 = *(const float4*)(sa + 4);
        *(uint4*)((char*)as_ + r * 128 + ((c * 16) ^ ((r & 7) << 4))) = pack8(a0, a1);
        const float* sb = pwt + (long)(n0 + r) * DM_ + k0 + c * 8;
        float4 b0 = *(const float4*)(sb);
        float4 b1 = *(const float4*)(sb + 4);
        *(uint4*)((char*)bs_ + r * 128 + ((c * 16) ^ ((r & 7) << 4))) = pack8(b0, b1);
      }
      __syncthreads();

      const char* arow = (const char*)as_ + (wid * 16 + l15) * 128;
      const int swz = (l15 & 7) << 4;
      s16x8 a0 = *(const s16x8*)(arow + ((l4 * 16) ^ swz));
      s16x8 a1 = *(const s16x8*)(arow + ((64 + l4 * 16) ^ swz));
      #pragma unroll
      for (int ct = 0; ct < 4; ++ct){
        const char* brow = (const char*)bs_ + (ct * 16 + l15) * 128;
        s16x8 b0 = *(const s16x8*)(brow + ((l4 * 16) ^ swz));
        s16x8 b1 = *(const s16x8*)(brow + ((64 + l4 * 16) ^ swz));
        acc[ct] = __builtin_amdgcn_mfma_f32_16x16x32_bf16(a0, b0, acc[ct], 0, 0, 0);
        acc[ct] = __builtin_amdgcn_mfma_f32_16x16x32_bf16(a1, b1, acc[ct], 0, 0, 0);
      }
    }

    #pragma unroll
    for (int ct = 0; ct < 4; ++ct){
      int col = n0 + ct * 16 + l15;
      #pragma unroll
      for (int r = 0; r < 4; ++r){
        int m = m0 + wid * 16 + l4 * 4 + r;
        w2b[(long)m * DM_ + col] = f2bfbits(acc[ct][r]);
      }
    }
  }
}

// ---------------------------------------------------------------------------
// K2: MFMA scores + branch-free top-1 softmax (round-12 verified, single kernel)
// ---------------------------------------------------------------------------
__global__ __launch_bounds__(256) void attn_top1_mfma(
    const ushort* __restrict__ qhb, const ushort* __restrict__ khb,
    float* __restrict__ pmax, int* __restrict__ amax){
  const int hb  = blockIdx.x;
  const int q0  = blockIdx.y * 64;
  const int tid = threadIdx.x;
  const int wid  = tid >> 6;
  const int lane = tid & 63;
  const int l15  = lane & 15;
  const int l4   = lane >> 4;

  __shared__ ushort ks[64 * 64];

  const ushort* qrow = qhb + ((long)hb * LQ_ + q0 + wid * 16 + l15) * DK_;
  s16x8 aq0 = *(const s16x8*)(qrow +  0 + l4 * 8);
  s16x8 aq1 = *(const s16x8*)(qrow + 32 + l4 * 8);

  const int i0 = tid, i1 = tid + 256;
  const int r0 = i0 >> 3, cg0 = (i0 & 7) ^ (r0 & 7);
  const int r1 = i1 >> 3, cg1 = (i1 & 7) ^ (r1 & 7);

  float m[4], sum[4]; int arg[4];
  #pragma unroll
  for (int r = 0; r < 4; ++r){ m[r] = -1e30f; sum[r] = 0.f; arg[r] = 0; }

  const ushort* kb0 = khb + (long)hb * LQ_ * DK_;
  for (int jt = 0; jt < LQ_ / 64; ++jt){
    __syncthreads();
    const ushort* kbase = kb0 + (long)(jt * 64) * DK_;
    gload_lds16(kbase + r0 * 64 + cg0 * 8, (char*)ks + i0 * 16);
    gload_lds16(kbase + r1 * 64 + cg1 * 8, (char*)ks + i1 * 16);
    __syncthreads();

    f32x4 acc[4];
    #pragma unroll
    for (int ct = 0; ct < 4; ++ct){
      int row = ct * 16 + l15;
      const char* base = (const char*)ks + row * 128;
      int swz = (row & 7) << 4;
      s16x8 b0 = *(const s16x8*)(base + ((l4 * 16) ^ swz));
      s16x8 b1 = *(const s16x8*)(base + ((64 + l4 * 16) ^ swz));
      f32x4 c; c[0]=0.f; c[1]=0.f; c[2]=0.f; c[3]=0.f;
      c = __builtin_amdgcn_mfma_f32_16x16x32_bf16(aq0, b0, c, 0, 0, 0);
      c = __builtin_amdgcn_mfma_f32_16x16x32_bf16(aq1, b1, c, 0, 0, 0);
      acc[ct] = c;
    }

    #pragma unroll
    for (int ct = 0; ct < 4; ++ct){
      int col = jt * 64 + ct * 16 + l15;
      #pragma unroll
      for (int r = 0; r < 4; ++r){
        float t = acc[ct][r];
        sum[r] += exp2f(t);
        bool gt = t > m[r];
        arg[r] = gt ? col : arg[r];
        m[r]   = gt ? t : m[r];
      }
    }
  }

  #pragma unroll
  for (int off = 1; off < 16; off <<= 1){
    #pragma unroll
    for (int r = 0; r < 4; ++r){
      float m2 = __shfl_xor(m[r], off);
      float s2 = __shfl_xor(sum[r], off);
      int   a2 = __shfl_xor(arg[r], off);
      sum[r] += s2;
      bool take = (m2 > m[r]) || (m2 == m[r] && a2 < arg[r]);
      arg[r] = take ? a2 : arg[r];
      m[r]   = take ? m2 : m[r];
    }
  }

  if (l15 == 0){
    #pragma unroll
    for (int r = 0; r < 4; ++r){
      long row = (long)hb * LQ_ + q0 + wid * 16 + l4 * 4 + r;
      pmax[row] = exp2f(m[r]) / sum[r];
      amax[row] = arg[r];
    }
  }
}

// ---------------------------------------------------------------------------
// Final GEMM body (round-12 verified): out0 = [q | p*vh[amax]] @ [lwb1|w2b]^T + bias2
// ---------------------------------------------------------------------------
__device__ __forceinline__ void gemm_final_body(
    int bid, const float* __restrict__ q, const float* __restrict__ vh,
    const ushort* __restrict__ lwb1, const ushort* __restrict__ w2b,
    const float* __restrict__ bias2, const float* __restrict__ pmax,
    const int* __restrict__ amax, float* __restrict__ out0){
  const int lt  = (bid & 7) * 64 + (bid >> 3);
  const int m0  = (lt >> 3) * 64;
  const int n0  = (lt & 7) * 64;

  const int tid = threadIdx.x;
  const int wid = tid >> 6, lane = tid & 63;
  const int l15 = lane & 15, l4 = lane >> 4;

  __shared__ ushort as_[64 * 64];
  __shared__ ushort bs_[64 * 64];

  f32x4 acc[4];
  #pragma unroll
  for (int ct = 0; ct < 4; ++ct){ acc[ct][0]=0.f; acc[ct][1]=0.f; acc[ct][2]=0.f; acc[ct][3]=0.f; }

  for (int k0 = 0; k0 < 2 * DM_; k0 += 64){
    __syncthreads();
    if (k0 < DM_){
      for (int i = tid; i < 512; i += 256){
        int r = i >> 3, c = i & 7;
        const float* sa = q + (long)(m0 + r) * DM_ + k0 + c * 8;
        float4 a0 = *(const float4*)(sa);
        float4 a1 = *(const float4*)(sa + 4);
        *(uint4*)((char*)as_ + r * 128 + ((c * 16) ^ ((r & 7) << 4))) = pack8(a0, a1);
        uint4 bv = *(const uint4*)(lwb1 + (long)(n0 + r) * DM_ + k0 + c * 8);
        *(uint4*)((char*)bs_ + r * 128 + ((c * 16) ^ ((r & 7) << 4))) = bv;
      }
    } else {
      const int kk = k0 - DM_;
      const int h  = kk >> 6;          // head is uniform across the tile
      for (int i = tid; i < 512; i += 256){
        int r = i >> 3, c = i & 7;
        int mm = m0 + r;
        int b = mm >> 11, l = mm & 2047;
        long hbrow = (long)(h * B_ + b) * LQ_;
        float p = pmax[hbrow + l];
        int  a  = amax[hbrow + l];
        const float* vrow = vh + (hbrow + a) * DK_ + c * 8;
        float4 a0 = *(const float4*)(vrow);
        float4 a1 = *(const float4*)(vrow + 4);
        a0.x *= p; a0.y *= p; a0.z *= p; a0.w *= p;
        a1.x *= p; a1.y *= p; a1.z *= p; a1.w *= p;
        *(uint4*)((char*)as_ + r * 128 + ((c * 16) ^ ((r & 7) << 4))) = pack8(a0, a1);
        uint4 bv = *(const uint4*)(w2b + (long)(n0 + r) * DM_ + kk + c * 8);
        *(uint4*)((char*)bs_ + r * 128 + ((c * 16) ^ ((r & 7) << 4))) = bv;
      }
    }
    __syncthreads();

    const char* arow = (const char*)as_ + (wid * 16 + l15) * 128;
    const int swz = (l15 & 7) << 4;
    s16x8 a0 = *(const s16x8*)(arow + ((l4 * 16) ^ swz));
    s16x8 a1 = *(const s16x8*)(arow + ((64 + l4 * 16) ^ swz));
    #pragma unroll
    for (int ct = 0; ct < 4; ++ct){
      const char* brow = (const char*)bs_ + (ct * 16 + l15) * 128;
      s16x8 b0 = *(const s16x8*)(brow + ((l4 * 16) ^ swz));
      s16x8 b1 = *(const s16x8*)(brow + ((64 + l4 * 16) ^ swz));
      acc[ct] = __builtin_amdgcn_mfma_f32_16x16x32_bf16(a0, b0, acc[ct], 0, 0, 0);
      acc[ct] = __builtin_amdgcn_mfma_f32_16x16x32_bf16(a1, b1, acc[ct], 0, 0, 0);
    }
  }

  #pragma unroll
  for (int ct = 0; ct < 4; ++ct){
    int col = n0 + ct * 16 + l15;
    float bb = bias2[col];
    #pragma unroll
    for (int r = 0; r < 4; ++r){
      int mm = m0 + wid * 16 + l4 * 4 + r;
      out0[(long)mm * DM_ + col] = acc[ct][r] + bb;
    }
  }
}

// ---------------------------------------------------------------------------
// Zero + scatter one group of 4 attn rows (round-12 verified).
// ---------------------------------------------------------------------------
__device__ __forceinline__ void write_attn_body(
    int bid, const float* __restrict__ pmax, const int* __restrict__ amax,
    float* __restrict__ attn_out){
  int row  = bid * 4 + (threadIdx.x >> 6);
  int lane = threadIdx.x & 63;
  float p = pmax[row];
  int a = amax[row];
  float4* rowp = (float4*)(attn_out + (long)row * LQ_);
  #pragma unroll
  for (int i = 0; i < 8; ++i){
    int f4idx = i * 64 + lane;
    int col0  = f4idx * 4;
    float4 z = make_float4(0.f, 0.f, 0.f, 0.f);
    if (a >= col0 && a < col0 + 4){
      int r = a - col0;
      if      (r == 0) z.x = p;
      else if (r == 1) z.y = p;
      else if (r == 2) z.z = p;
      else             z.w = p;
    }
    rowp[f4idx] = z;
  }
}

// Standalone kernels (legacy path)
__global__ __launch_bounds__(256) void gemm_final_k(
    const float* __restrict__ q, const float* __restrict__ vh,
    const ushort* __restrict__ lwb1, const ushort* __restrict__ w2b,
    const float* __restrict__ bias2, const float* __restrict__ pmax,
    const int* __restrict__ amax, float* __restrict__ out0){
  gemm_final_body(blockIdx.x, q, vh, lwb1, w2b, bias2, pmax, amax, out0);
}
__global__ __launch_bounds__(256) void write_attn_k(
    const float* __restrict__ pmax, const int* __restrict__ amax,
    float* __restrict__ attn_out){
  write_attn_body(blockIdx.x, pmax, amax, attn_out);
}

// Fused heterogeneous dispatch (scratch fully in d_ws): blocks 0..511 = GEMM,
// 512..8703 = attn-region zero+scatter. No block reads the attn region.
__global__ __launch_bounds__(256) void final_fused_k(
    const float* __restrict__ q, const float* __restrict__ vh,
    const ushort* __restrict__ lwb1, const ushort* __restrict__ w2b,
    const float* __restrict__ bias2, const float* __restrict__ pmax,
    const int* __restrict__ amax, float* __restrict__ out0,
    float* __restrict__ attn_out){
  if (blockIdx.x < 512)
    gemm_final_body(blockIdx.x, q, vh, lwb1, w2b, bias2, pmax, amax, out0);
  else
    write_attn_body(blockIdx.x - 512, pmax, amax, attn_out);
}

// ---------------------------------------------------------------------------
extern "C" void kernel_launch(void* const* d_in, const int* in_sizes, int n_in,
                              void* d_out, int out_size, void* d_ws, size_t ws_size,
                              hipStream_t stream){
  const float* q  = (const float*)d_in[0];
  const float* k  = (const float*)d_in[1];
  const float* v  = (const float*)d_in[2];
  const float* wq = (const float*)d_in[3];
  const float* wk = (const float*)d_in[4];
  const float* wv = (const float*)d_in[5];
  const float* pw = (const float*)d_in[6];
  const float* pb = (const float*)d_in[7];
  const float* lw = (const float*)d_in[8];
  const float* lb = (const float*)d_in[9];

  float* out0     = (float*)d_out;                    // (2,2048,512)
  float* attn_out = out0 + (long)B_ * LQ_ * DM_;      // (16,2048,2048)

  // Stats always in d_ws.
  float* pmax = (float*)d_ws;                          // 16*2048 floats
  int*   amax = (int*)(pmax + (long)HB_ * LQ_);        // 16*2048 ints

  // Fused path needs vh + lwb1 + w2b + bias2 in d_ws.
  const size_t WS_FUSED_NEED = (size_t)HB_*LQ_*8
                             + (size_t)DM_*4 + 4096
                             + (size_t)HB_*LQ_*DK_*4
                             + (size_t)DM_*DM_*2*2;
  const bool fused = (ws_size >= WS_FUSED_NEED + (1u<<20));

  float *vh, *bias2; ushort *lwb1, *w2b;
  if (fused){
    float* p = (float*)(amax + (long)HB_ * LQ_);
    bias2 = p;                        p += DM_ + 256;
    vh    = p;                        p += (long)HB_ * LQ_ * DK_;
    lwb1  = (ushort*)p;
    w2b   = lwb1 + (long)DM_ * DM_;
  } else {
    vh    = attn_out;
    bias2 = vh + (long)HB_ * LQ_ * DK_;
    lwb1  = (ushort*)(bias2 + DM_ + 256);
    w2b   = lwb1 + (long)DM_ * DM_;
  }

  // Scratch only read BEFORE the final dispatch lives in the attn region.
  ushort* base = fused ? (ushort*)attn_out : (w2b + (long)DM_ * DM_);
  ushort* wqT  = base;
  ushort* wkT  = wqT + (long)DM_ * DM_;
  ushort* wvT  = wkT + (long)DM_ * DM_;
  float*  pwt  = (float*)(wvT + (long)DM_ * DM_);
  ushort* qhb  = (ushort*)(pwt + (long)DM_ * DM_);
  ushort* khb  = qhb + (long)HB_ * LQ_ * DK_;
  // attn-region scratch total ~14 MB << 268 MB

  // 1) weight prep (tiny)
  prep_all<<<dim3(64, 1, 6), 256, 0, stream>>>(
      wq, wk, wv, pw, lw, pb, lb, wqT, wkT, wvT, pwt, bias2, lwb1);

  // 2) qkv GEMMs (cast-on-stage) + W2 in one launch
  phase2_k<<<1600, 256, 0, stream>>>(
      q, k, v, wqT, wkT, wvT, qhb, khb, vh, lw, pwt, w2b);

  // 3) MFMA scores + branch-free top-1 softmax
  attn_top1_mfma<<<dim3(HB_, LQ_/64), 256, 0, stream>>>(qhb, khb, pmax, amax);

  // 4) final GEMM + attn-region write
  if (fused){
    final_fused_k<<<512 + HB_*LQ_/4, 256, 0, stream>>>(
        q, vh, lwb1, w2b, bias2, pmax, amax, out0, attn_out);
  } else {
    gemm_final_k<<<512, 256, 0, stream>>>(q, vh, lwb1, w2b, bias2, pmax, amax, out0);
    write_attn_k<<<HB_*LQ_/4, 256, 0, stream>>>(pmax, amax, attn_out);
  }
}